// Round 1
// baseline (985.528 us; speedup 1.0000x reference)
//
#include <hip/hip_runtime.h>
#include <math.h>

#define HEAD 128

// ---------------- compile-time Möbius band table ----------------
constexpr int mu_of(int n) {
  int m = n, cnt = 0;
  for (int p = 2; p * p <= m; ++p) {
    if (m % p == 0) {
      m /= p; ++cnt;
      if (m % p == 0) return 0;
    }
  }
  if (m > 1) ++cnt;
  return (cnt & 1) ? -1 : 1;
}

// stable argsort key of -mu: mu=1 -> 0, mu=0 -> 1, mu=-1 -> 2
constexpr int key_of(int idx) {
  int mu = mu_of(idx + 1);
  return mu == 1 ? 0 : (mu == 0 ? 1 : 2);
}

struct Tbl {
  int band[HEAD];
  float qm[HEAD];
};

constexpr Tbl make_tbl() {
  Tbl t{};
  constexpr float qv[4] = {15.f, 7.f, 7.f, 3.f};  // 2^(b-1)-1 for bits 5,4,4,3
  for (int p = 0; p < HEAD; ++p) {
    int kp = key_of(p);
    int rank = 0;
    for (int j = 0; j < HEAD; ++j) {
      int kj = key_of(j);
      if (kj < kp || (kj == kp && j < p)) ++rank;
    }
    t.band[p] = rank >> 5;
    t.qm[p] = qv[rank >> 5];
  }
  return t;
}

__constant__ Tbl g_tbl = make_tbl();

// ---------------- GEMM: C[M,N] = A[M,K] @ B[N,K]^T + bias ----------------
#define BM 128
#define BN 64
#define BKK 8
#define TM 8
#define TN 4

__global__ __launch_bounds__(256) void sgemm_nt(
    const float* __restrict__ A, const float* __restrict__ B,
    const float* __restrict__ bias, float* __restrict__ C,
    int M, int N, int K) {
  __shared__ float As[BKK][BM];
  __shared__ float Bs[BKK][BN];

  const int tid = threadIdx.x;
  const int tn = tid & 15;   // 0..15  -> col group
  const int tm = tid >> 4;   // 0..15  -> row group
  const int bx = blockIdx.x; // N tile
  const int by = blockIdx.y; // M tile

  const float* Ab = A + (size_t)by * BM * K;
  const float* Bb = B + (size_t)bx * BN * K;

  const int ar = tid >> 1;        // 0..127 (A rows); 0..63 for B when tid<128
  const int ak = (tid & 1) * 4;   // 0 or 4

  float acc[TM][TN];
#pragma unroll
  for (int i = 0; i < TM; ++i)
#pragma unroll
    for (int j = 0; j < TN; ++j) acc[i][j] = 0.f;

  for (int k0 = 0; k0 < K; k0 += BKK) {
    float4 av = *(const float4*)(Ab + (size_t)ar * K + k0 + ak);
    float4 bv = make_float4(0.f, 0.f, 0.f, 0.f);
    if (tid < 128) bv = *(const float4*)(Bb + (size_t)ar * K + k0 + ak);

    __syncthreads();  // previous iter's LDS reads complete
    As[ak + 0][ar] = av.x;
    As[ak + 1][ar] = av.y;
    As[ak + 2][ar] = av.z;
    As[ak + 3][ar] = av.w;
    if (tid < 128) {
      Bs[ak + 0][ar] = bv.x;
      Bs[ak + 1][ar] = bv.y;
      Bs[ak + 2][ar] = bv.z;
      Bs[ak + 3][ar] = bv.w;
    }
    __syncthreads();

#pragma unroll
    for (int kk = 0; kk < BKK; ++kk) {
      float a[TM], b[TN];
#pragma unroll
      for (int i = 0; i < TM; ++i) a[i] = As[kk][tm * TM + i];
#pragma unroll
      for (int j = 0; j < TN; ++j) b[j] = Bs[kk][tn * TN + j];
#pragma unroll
      for (int i = 0; i < TM; ++i)
#pragma unroll
        for (int j = 0; j < TN; ++j) acc[i][j] += a[i] * b[j];
    }
  }

  const int row0 = by * BM + tm * TM;
  const int col0 = bx * BN + tn * TN;
  float bj[TN];
#pragma unroll
  for (int j = 0; j < TN; ++j) bj[j] = bias[col0 + j];
#pragma unroll
  for (int i = 0; i < TM; ++i) {
    float4 v = make_float4(acc[i][0] + bj[0], acc[i][1] + bj[1],
                           acc[i][2] + bj[2], acc[i][3] + bj[3]);
    *(float4*)(C + (size_t)(row0 + i) * N + col0) = v;
  }
}

// ---------------- Hadamard + banded quant-dequant + inverse ----------------
// One wave per 128-row; lane holds elements [lane] and [lane+64].
__device__ inline void fwht2(float& e0, float& e1, int lane) {
  // stride 64: intra-lane
  float a = e0 + e1;
  float b = e0 - e1;
  e0 = a;
  e1 = b;
#pragma unroll
  for (int s = 1; s <= 32; s <<= 1) {
    float p0 = __shfl_xor(e0, s);
    float p1 = __shfl_xor(e1, s);
    bool up = (lane & s) != 0;
    e0 = up ? (p0 - e0) : (e0 + p0);
    e1 = up ? (p1 - e1) : (e1 + p1);
  }
}

__global__ __launch_bounds__(256) void hadq(const float* __restrict__ Y,
                                            float* __restrict__ O, int nrows) {
  const int lane = threadIdx.x & 63;
  const int wave = (blockIdx.x * (blockDim.x >> 6)) + (threadIdx.x >> 6);
  const int nwaves = gridDim.x * (blockDim.x >> 6);

  const int b0 = g_tbl.band[lane];
  const int b1 = g_tbl.band[lane + 64];
  const float qm0 = g_tbl.qm[lane];
  const float qm1 = g_tbl.qm[lane + 64];

  for (int row = wave; row < nrows; row += nwaves) {
    const float* y = Y + (size_t)row * HEAD;
    float e0 = y[lane];
    float e1 = y[lane + 64];

    fwht2(e0, e1, lane);  // z = y @ H

    // per-band amax (bands are scattered index sets; perms cancel on data)
    float f0 = fabsf(e0), f1 = fabsf(e1);
    float ab0 = fmaxf(b0 == 0 ? f0 : 0.f, b1 == 0 ? f1 : 0.f);
    float ab1 = fmaxf(b0 == 1 ? f0 : 0.f, b1 == 1 ? f1 : 0.f);
    float ab2 = fmaxf(b0 == 2 ? f0 : 0.f, b1 == 2 ? f1 : 0.f);
    float ab3 = fmaxf(b0 == 3 ? f0 : 0.f, b1 == 3 ? f1 : 0.f);
#pragma unroll
    for (int s = 32; s >= 1; s >>= 1) {
      ab0 = fmaxf(ab0, __shfl_xor(ab0, s));
      ab1 = fmaxf(ab1, __shfl_xor(ab1, s));
      ab2 = fmaxf(ab2, __shfl_xor(ab2, s));
      ab3 = fmaxf(ab3, __shfl_xor(ab3, s));
    }
    float am0 = b0 == 0 ? ab0 : (b0 == 1 ? ab1 : (b0 == 2 ? ab2 : ab3));
    float am1 = b1 == 0 ? ab0 : (b1 == 1 ? ab1 : (b1 == 2 ? ab2 : ab3));

    float s0 = am0 > 0.f ? am0 / qm0 : 1.0f;
    float s1 = am1 > 0.f ? am1 / qm1 : 1.0f;

    // round-half-even like jnp.round, then clip, then dequant
    float q0 = fminf(fmaxf(rintf(e0 / s0), -qm0), qm0);
    float q1 = fminf(fmaxf(rintf(e1 / s1), -qm1), qm1);
    e0 = q0 * s0;
    e1 = q1 * s1;

    fwht2(e0, e1, lane);  // back through H
    float r0 = e0 * 0.0078125f;  // /128
    float r1 = e1 * 0.0078125f;
    if (r0 != r0) r0 = 0.f;  // nan_to_num
    if (r1 != r1) r1 = 0.f;
    r0 = fminf(fmaxf(r0, -65504.f), 65504.f);
    r1 = fminf(fmaxf(r1, -65504.f), 65504.f);

    float* o = O + (size_t)row * HEAD;
    o[lane] = r0;
    o[lane + 64] = r1;
  }
}

// ---------------- launch ----------------
extern "C" void kernel_launch(void* const* d_in, const int* in_sizes, int n_in,
                              void* d_out, int out_size, void* d_ws, size_t ws_size,
                              hipStream_t stream) {
  const float* x = (const float*)d_in[0];
  const float* W = (const float*)d_in[1];
  const float* b = (const float*)d_in[2];
  float* out = (float*)d_out;

  const int N = in_sizes[2];          // 5120
  const int K = N;                    // 5120
  const int M = in_sizes[0] / K;      // 1024

  dim3 grid(N / BN, M / BM);
  sgemm_nt<<<grid, 256, 0, stream>>>(x, W, b, out, M, N, K);

  const int nrows = out_size / HEAD;  // 40960
  hadq<<<512, 256, 0, stream>>>(out, out, nrows);
}

// Round 2
// 493.686 us; speedup vs baseline: 1.9963x; 1.9963x over previous
//
#include <hip/hip_runtime.h>
#include <math.h>

#define HEAD 128
typedef _Float16 f16;
typedef _Float16 f16x8 __attribute__((ext_vector_type(8)));
typedef _Float16 f16x4 __attribute__((ext_vector_type(4)));
typedef float f32x4 __attribute__((ext_vector_type(4)));

// ---------------- compile-time Möbius band table ----------------
constexpr int mu_of(int n) {
  int m = n, cnt = 0;
  for (int p = 2; p * p <= m; ++p) {
    if (m % p == 0) {
      m /= p; ++cnt;
      if (m % p == 0) return 0;
    }
  }
  if (m > 1) ++cnt;
  return (cnt & 1) ? -1 : 1;
}
constexpr int key_of(int idx) {
  int mu = mu_of(idx + 1);
  return mu == 1 ? 0 : (mu == 0 ? 1 : 2);
}
struct Tbl {
  int band[HEAD];
  float qm[HEAD];
};
constexpr Tbl make_tbl() {
  Tbl t{};
  constexpr float qv[4] = {15.f, 7.f, 7.f, 3.f};
  for (int p = 0; p < HEAD; ++p) {
    int kp = key_of(p);
    int rank = 0;
    for (int j = 0; j < HEAD; ++j) {
      int kj = key_of(j);
      if (kj < kp || (kj == kp && j < p)) ++rank;
    }
    t.band[p] = rank >> 5;
    t.qm[p] = qv[rank >> 5];
  }
  return t;
}
__constant__ Tbl g_tbl = make_tbl();

// ---------------- f32 -> (hi,lo) f16 split, pre-scaled by 64 ----------------
__global__ __launch_bounds__(256) void split64(const float* __restrict__ s,
                                               f16* __restrict__ h,
                                               f16* __restrict__ l, int n4) {
  int i = blockIdx.x * blockDim.x + threadIdx.x;
  if (i >= n4) return;
  float4 v = ((const float4*)s)[i];
  v.x *= 64.f; v.y *= 64.f; v.z *= 64.f; v.w *= 64.f;
  f16 hx = (f16)v.x, hy = (f16)v.y, hz = (f16)v.z, hw = (f16)v.w;
  f16 lx = (f16)(v.x - (float)hx);
  f16 ly = (f16)(v.y - (float)hy);
  f16 lz = (f16)(v.z - (float)hz);
  f16 lw = (f16)(v.w - (float)hw);
  f16x4 hv = {hx, hy, hz, hw};
  f16x4 lv = {lx, ly, lz, lw};
  *(f16x4*)(h + 4 * (size_t)i) = hv;
  *(f16x4*)(l + 4 * (size_t)i) = lv;
}

// ---------------- async global->LDS, 16B ----------------
__device__ __forceinline__ void dma16(const f16* g, f16* l) {
  __builtin_amdgcn_global_load_lds(
      (const __attribute__((address_space(1))) unsigned int*)g,
      (__attribute__((address_space(3))) unsigned int*)l, 16, 0, 0);
}

// ---------------- MFMA GEMM: C[M,N] = (Ah+Al)(Bh+Bl)^T /4096 + bias --------
// 1 wave per block; 64x64 tile; BK=32; 3-term f16 split (AlBl dropped).
__global__ __launch_bounds__(64) void gemm_f16split(
    const f16* __restrict__ Ah, const f16* __restrict__ Al,
    const f16* __restrict__ Bh, const f16* __restrict__ Bl,
    const float* __restrict__ bias, float* __restrict__ C,
    int M, int N, int K) {
  __shared__ f16 sAh[64 * 32];
  __shared__ f16 sAl[64 * 32];
  __shared__ f16 sBh[64 * 32];
  __shared__ f16 sBl[64 * 32];

  const int lane = threadIdx.x;
  const int m0 = blockIdx.x * 64;
  const int n0 = blockIdx.y * 64;

  // staging: lane loads 16B at row (lane>>2), col (lane&3)*8 of the tile
  const int srow = lane >> 2;
  const int scol = (lane & 3) * 8;
  const f16* gAh = Ah + (size_t)(m0 + srow) * K + scol;
  const f16* gAl = Al + (size_t)(m0 + srow) * K + scol;
  const f16* gBh = Bh + (size_t)(n0 + srow) * K + scol;
  const f16* gBl = Bl + (size_t)(n0 + srow) * K + scol;
  const size_t rstep = (size_t)16 * K;

  f32x4 acc[4][4];
#pragma unroll
  for (int i = 0; i < 4; ++i)
#pragma unroll
    for (int j = 0; j < 4; ++j) acc[i][j] = (f32x4){0.f, 0.f, 0.f, 0.f};

  // stage tile 0
#pragma unroll
  for (int j = 0; j < 4; ++j) {
    dma16(gAh + j * rstep, &sAh[j * 512]);
    dma16(gAl + j * rstep, &sAl[j * 512]);
    dma16(gBh + j * rstep, &sBh[j * 512]);
    dma16(gBl + j * rstep, &sBl[j * 512]);
  }

  const int frow = lane & 15;
  const int kq = lane >> 4;  // 0..3
  const int fbase = frow * 32 + kq * 8;

  for (int k0 = 0; k0 < K; k0 += 32) {
    __syncthreads();  // vmcnt(0): tile k0 resident in LDS
    f16x8 ah[4], al[4], bh[4], bl[4];
#pragma unroll
    for (int s = 0; s < 4; ++s) {
      ah[s] = *(const f16x8*)&sAh[s * 512 + fbase];
      al[s] = *(const f16x8*)&sAl[s * 512 + fbase];
      bh[s] = *(const f16x8*)&sBh[s * 512 + fbase];
      bl[s] = *(const f16x8*)&sBl[s * 512 + fbase];
    }
    __syncthreads();  // lgkmcnt(0): frags in regs; LDS safe to overwrite
    if (k0 + 32 < K) {
      const int kn = k0 + 32;
#pragma unroll
      for (int j = 0; j < 4; ++j) {
        dma16(gAh + kn + j * rstep, &sAh[j * 512]);
        dma16(gAl + kn + j * rstep, &sAl[j * 512]);
        dma16(gBh + kn + j * rstep, &sBh[j * 512]);
        dma16(gBl + kn + j * rstep, &sBl[j * 512]);
      }
    }
#pragma unroll
    for (int i = 0; i < 4; ++i)
#pragma unroll
      for (int j = 0; j < 4; ++j) {
        acc[i][j] = __builtin_amdgcn_mfma_f32_16x16x32_f16(ah[i], bh[j], acc[i][j], 0, 0, 0);
        acc[i][j] = __builtin_amdgcn_mfma_f32_16x16x32_f16(al[i], bh[j], acc[i][j], 0, 0, 0);
        acc[i][j] = __builtin_amdgcn_mfma_f32_16x16x32_f16(ah[i], bl[j], acc[i][j], 0, 0, 0);
      }
  }

  // epilogue: C/D layout col=lane&15, row=(lane>>4)*4+r
  const float inv = 1.f / 4096.f;
#pragma unroll
  for (int j = 0; j < 4; ++j) {
    const int col = n0 + j * 16 + frow;
    const float bv = bias[col];
#pragma unroll
    for (int i = 0; i < 4; ++i) {
#pragma unroll
      for (int r = 0; r < 4; ++r) {
        const int row = m0 + i * 16 + kq * 4 + r;
        C[(size_t)row * N + col] = acc[i][j][r] * inv + bv;
      }
    }
  }
}

// ---------------- fallback fp32 GEMM (proven) ----------------
#define BM 128
#define BN 64
#define BKK 8
#define TM 8
#define TN 4

__global__ __launch_bounds__(256) void sgemm_nt(
    const float* __restrict__ A, const float* __restrict__ B,
    const float* __restrict__ bias, float* __restrict__ C,
    int M, int N, int K) {
  __shared__ float As[BKK][BM];
  __shared__ float Bs[BKK][BN];

  const int tid = threadIdx.x;
  const int tn = tid & 15;
  const int tm = tid >> 4;
  const int bx = blockIdx.x;
  const int by = blockIdx.y;

  const float* Ab = A + (size_t)by * BM * K;
  const float* Bb = B + (size_t)bx * BN * K;

  const int ar = tid >> 1;
  const int ak = (tid & 1) * 4;

  float acc[TM][TN];
#pragma unroll
  for (int i = 0; i < TM; ++i)
#pragma unroll
    for (int j = 0; j < TN; ++j) acc[i][j] = 0.f;

  for (int k0 = 0; k0 < K; k0 += BKK) {
    float4 av = *(const float4*)(Ab + (size_t)ar * K + k0 + ak);
    float4 bv = make_float4(0.f, 0.f, 0.f, 0.f);
    if (tid < 128) bv = *(const float4*)(Bb + (size_t)ar * K + k0 + ak);

    __syncthreads();
    As[ak + 0][ar] = av.x;
    As[ak + 1][ar] = av.y;
    As[ak + 2][ar] = av.z;
    As[ak + 3][ar] = av.w;
    if (tid < 128) {
      Bs[ak + 0][ar] = bv.x;
      Bs[ak + 1][ar] = bv.y;
      Bs[ak + 2][ar] = bv.z;
      Bs[ak + 3][ar] = bv.w;
    }
    __syncthreads();

#pragma unroll
    for (int kk = 0; kk < BKK; ++kk) {
      float a[TM], b[TN];
#pragma unroll
      for (int i = 0; i < TM; ++i) a[i] = As[kk][tm * TM + i];
#pragma unroll
      for (int j = 0; j < TN; ++j) b[j] = Bs[kk][tn * TN + j];
#pragma unroll
      for (int i = 0; i < TM; ++i)
#pragma unroll
        for (int j = 0; j < TN; ++j) acc[i][j] += a[i] * b[j];
    }
  }

  const int row0 = by * BM + tm * TM;
  const int col0 = bx * BN + tn * TN;
  float bj[TN];
#pragma unroll
  for (int j = 0; j < TN; ++j) bj[j] = bias[col0 + j];
#pragma unroll
  for (int i = 0; i < TM; ++i) {
    float4 v = make_float4(acc[i][0] + bj[0], acc[i][1] + bj[1],
                           acc[i][2] + bj[2], acc[i][3] + bj[3]);
    *(float4*)(C + (size_t)(row0 + i) * N + col0) = v;
  }
}

// ---------------- Hadamard + banded quant-dequant + inverse ----------------
__device__ inline void fwht2(float& e0, float& e1, int lane) {
  float a = e0 + e1;
  float b = e0 - e1;
  e0 = a;
  e1 = b;
#pragma unroll
  for (int s = 1; s <= 32; s <<= 1) {
    float p0 = __shfl_xor(e0, s);
    float p1 = __shfl_xor(e1, s);
    bool up = (lane & s) != 0;
    e0 = up ? (p0 - e0) : (e0 + p0);
    e1 = up ? (p1 - e1) : (e1 + p1);
  }
}

__global__ __launch_bounds__(256) void hadq(const float* __restrict__ Y,
                                            float* __restrict__ O, int nrows) {
  const int lane = threadIdx.x & 63;
  const int wave = (blockIdx.x * (blockDim.x >> 6)) + (threadIdx.x >> 6);
  const int nwaves = gridDim.x * (blockDim.x >> 6);

  const int b0 = g_tbl.band[lane];
  const int b1 = g_tbl.band[lane + 64];
  const float qm0 = g_tbl.qm[lane];
  const float qm1 = g_tbl.qm[lane + 64];

  for (int row = wave; row < nrows; row += nwaves) {
    const float* y = Y + (size_t)row * HEAD;
    float e0 = y[lane];
    float e1 = y[lane + 64];

    fwht2(e0, e1, lane);

    float f0 = fabsf(e0), f1 = fabsf(e1);
    float ab0 = fmaxf(b0 == 0 ? f0 : 0.f, b1 == 0 ? f1 : 0.f);
    float ab1 = fmaxf(b0 == 1 ? f0 : 0.f, b1 == 1 ? f1 : 0.f);
    float ab2 = fmaxf(b0 == 2 ? f0 : 0.f, b1 == 2 ? f1 : 0.f);
    float ab3 = fmaxf(b0 == 3 ? f0 : 0.f, b1 == 3 ? f1 : 0.f);
#pragma unroll
    for (int s = 32; s >= 1; s >>= 1) {
      ab0 = fmaxf(ab0, __shfl_xor(ab0, s));
      ab1 = fmaxf(ab1, __shfl_xor(ab1, s));
      ab2 = fmaxf(ab2, __shfl_xor(ab2, s));
      ab3 = fmaxf(ab3, __shfl_xor(ab3, s));
    }
    float am0 = b0 == 0 ? ab0 : (b0 == 1 ? ab1 : (b0 == 2 ? ab2 : ab3));
    float am1 = b1 == 0 ? ab0 : (b1 == 1 ? ab1 : (b1 == 2 ? ab2 : ab3));

    float s0 = am0 > 0.f ? am0 / qm0 : 1.0f;
    float s1 = am1 > 0.f ? am1 / qm1 : 1.0f;

    float q0 = fminf(fmaxf(rintf(e0 / s0), -qm0), qm0);
    float q1 = fminf(fmaxf(rintf(e1 / s1), -qm1), qm1);
    e0 = q0 * s0;
    e1 = q1 * s1;

    fwht2(e0, e1, lane);
    float r0 = e0 * 0.0078125f;
    float r1 = e1 * 0.0078125f;
    if (r0 != r0) r0 = 0.f;
    if (r1 != r1) r1 = 0.f;
    r0 = fminf(fmaxf(r0, -65504.f), 65504.f);
    r1 = fminf(fmaxf(r1, -65504.f), 65504.f);

    float* o = O + (size_t)row * HEAD;
    o[lane] = r0;
    o[lane + 64] = r1;
  }
}

// ---------------- launch ----------------
extern "C" void kernel_launch(void* const* d_in, const int* in_sizes, int n_in,
                              void* d_out, int out_size, void* d_ws, size_t ws_size,
                              hipStream_t stream) {
  const float* x = (const float*)d_in[0];
  const float* W = (const float*)d_in[1];
  const float* b = (const float*)d_in[2];
  float* out = (float*)d_out;

  const int N = in_sizes[2];      // 5120
  const int K = N;                // 5120
  const int M = in_sizes[0] / K;  // 1024

  const size_t MK = (size_t)M * K;
  const size_t NK = (size_t)N * K;
  const size_t need = (MK + NK) * 2 * sizeof(f16);  // hi+lo for x and W

  if (ws_size >= need) {
    f16* xh = (f16*)d_ws;
    f16* xl = xh + MK;
    f16* wh = xl + MK;
    f16* wl = wh + NK;

    const int n4x = (int)(MK / 4);
    const int n4w = (int)(NK / 4);
    split64<<<(n4x + 255) / 256, 256, 0, stream>>>(x, xh, xl, n4x);
    split64<<<(n4w + 255) / 256, 256, 0, stream>>>(W, wh, wl, n4w);

    dim3 grid(M / 64, N / 64);  // 16 x 80: consecutive blocks share B slice
    gemm_f16split<<<grid, 64, 0, stream>>>(xh, xl, wh, wl, b, out, M, N, K);
  } else {
    dim3 grid(N / BN, M / BM);
    sgemm_nt<<<grid, 256, 0, stream>>>(x, W, b, out, M, N, K);
  }

  const int nrows = out_size / HEAD;
  hadq<<<512, 256, 0, stream>>>(out, out, nrows);
}